// Round 6
// baseline (367.108 us; speedup 1.0000x reference)
//
#include <hip/hip_runtime.h>
#include <hip/hip_bf16.h>
#include <math.h>

// Problem constants (fixed by the harness)
#define Bq    8
#define Nq    50000
#define CIN   32
#define Sq    9
#define COUT  64
#define MSEG  12500
#define NNZq  50000
#define KSTEPS 9          // 288 / 32

#define WT_BYTES 65536                      // ws[0..64K): W^T bf16 (36,864 B used)
#define XB_BYTES ((size_t)Bq*Nq*CIN*2)      // 25.6 MB bf16 x copy

typedef __bf16 bf16x8 __attribute__((ext_vector_type(8)));
typedef float  f32x4  __attribute__((ext_vector_type(4)));

static __device__ __forceinline__ unsigned short f2bf(float f) {
  union { float f; unsigned u; } v; v.f = f;
  unsigned r = v.u + 0x7fffu + ((v.u >> 16) & 1u);   // RNE
  return (unsigned short)(r >> 16);
}

// Prep A: W[288][64] f32 -> WT[64][288] bf16 (tiny; L1/L2-resident after)
__global__ __launch_bounds__(256) void prep_wt(const float* __restrict__ W,
                                               unsigned short* __restrict__ WT)
{
  int t = blockIdx.x * 256 + threadIdx.x;     // 18432 elems
  if (t >= 288 * 64) return;
  int c = t & 63;
  int k = t >> 6;
  WT[c * 288 + k] = f2bf(W[k * 64 + c]);
}

// Prep B: x f32 -> xb bf16 (12.8M elems; per-batch slice 3.2MB fits one XCD L2)
__global__ __launch_bounds__(256) void prep_xb(const float* __restrict__ x,
                                               unsigned short* __restrict__ xb)
{
  int i = blockIdx.x * 256 + threadIdx.x;     // 4 elems per thread; 12500 blocks exact
  float4 v = ((const float4*)x)[i];
  ushort4 p;
  p.x = f2bf(v.x); p.y = f2bf(v.y); p.z = f2bf(v.z); p.w = f2bf(v.w);
  ((ushort4*)xb)[i] = p;
}

// Kernel 1: fused gather + GEMM(288x64 bf16 MFMA) + bias + ELU -> h (bf16)
// No LDS. Lane gathers its 16-B A-fragment straight from xb (L2-hot per XCD via
// bid&7 batch affinity). h layout [n][bloc][c], bf16.
__global__ __launch_bounds__(256, 4) void fused_gather_gemm_elu(
    const unsigned short* __restrict__ xb, const unsigned short* __restrict__ WT,
    const float* __restrict__ bias, const int* __restrict__ sidx,
    unsigned short* __restrict__ h, int bbase, int nb, int lgnb)
{
  const int tid  = threadIdx.x;
  const int bid  = blockIdx.x;
  const int bloc = bid & (nb - 1);
  const int n0   = (bid >> lgnb) * 64;
  const int b    = bbase + bloc;

  const int w  = tid >> 6;
  const int l  = tid & 63;
  const int la = l & 15;
  const int kg = l >> 4;

  int nrow   = n0 + w * 16 + la;
  int nclamp = nrow < Nq ? nrow : Nq - 1;

  int idxs[KSTEPS];
  #pragma unroll
  for (int s = 0; s < KSTEPS; ++s) idxs[s] = sidx[nclamp * Sq + s];

  const unsigned short* xbb = xb + (size_t)b * Nq * CIN + kg * 8;
  const __bf16* wb = (const __bf16*)WT + la * 288 + kg * 8;

  f32x4 acc[4];
  #pragma unroll
  for (int i = 0; i < 4; ++i) acc[i] = (f32x4){0.f, 0.f, 0.f, 0.f};

  #pragma unroll
  for (int ks = 0; ks < KSTEPS; ++ks) {
    bf16x8 a = *(const bf16x8*)(xbb + (size_t)idxs[ks] * CIN);  // one 16-B load
    #pragma unroll
    for (int ct = 0; ct < 4; ++ct) {
      bf16x8 bb = *(const bf16x8*)(wb + ct * 16 * 288 + ks * 32);
      acc[ct] = __builtin_amdgcn_mfma_f32_16x16x32_bf16(a, bb, acc[ct], 0, 0, 0);
    }
  }

  // epilogue: bias + ELU, store h bf16 [n][bloc][c]
  #pragma unroll
  for (int ct = 0; ct < 4; ++ct) {
    int cn = ct * 16 + la;
    float bv = bias[cn];
    #pragma unroll
    for (int r = 0; r < 4; ++r) {
      int n = n0 + w * 16 + kg * 4 + r;     // D: row = 4*(lane>>4)+reg, col = lane&15
      if (n < Nq) {
        float v = acc[ct][r] + bv;
        v = v > 0.f ? v : (__expf(v) - 1.0f);  // ELU(alpha=1)
        h[((size_t)n * nb + bloc) * COUT + cn] = f2bf(v);
      }
    }
  }
}

// Kernel 2: scatter-add pooling. nb==8: one block per edge -> row/col/value are
// wave-uniform (scalar loads); h row read as 1KB contiguous ushort2 per thread.
__global__ __launch_bounds__(256) void scatter_pool(
    const unsigned short* __restrict__ h, const float* __restrict__ value,
    const int* __restrict__ row, const int* __restrict__ col,
    float* __restrict__ out, int bbase, int nb, int lgnb)
{
  int i    = blockIdx.x * 256 + threadIdx.x;
  int c2   = i & 31;                 // ushort2 index: channels 2*c2, 2*c2+1
  int bloc = (i >> 5) & (nb - 1);
  int e    = i >> (5 + lgnb);
  if (e >= NNZq) return;
  int   cc = col[e];
  int   rr = row[e];
  float v  = value[e];
  ushort2 hp = ((const ushort2*)(h + ((size_t)cc * nb + bloc) * COUT))[c2];
  float h0 = __bfloat162float(*(const __hip_bfloat16*)&hp.x);
  float h1 = __bfloat162float(*(const __hip_bfloat16*)&hp.y);
  float* op = &out[((size_t)(bbase + bloc) * MSEG + rr) * COUT + c2 * 2];
  atomicAdd(op + 0, h0 * v);
  atomicAdd(op + 1, h1 * v);
}

extern "C" void kernel_launch(void* const* d_in, const int* in_sizes, int n_in,
                              void* d_out, int out_size, void* d_ws, size_t ws_size,
                              hipStream_t stream)
{
  const float* x     = (const float*)d_in[0];
  const float* W     = (const float*)d_in[1];
  const float* bias  = (const float*)d_in[2];
  const float* value = (const float*)d_in[3];
  const int*   sidx  = (const int*)d_in[4];
  const int*   row   = (const int*)d_in[5];
  const int*   col   = (const int*)d_in[6];
  float* out = (float*)d_out;

  unsigned short* WT = (unsigned short*)d_ws;
  unsigned short* xb = (unsigned short*)((char*)d_ws + WT_BYTES);
  unsigned short* h  = (unsigned short*)((char*)d_ws + WT_BYTES + XB_BYTES);

  size_t per_batch = (size_t)Nq * COUT * 2;               // 6.4 MB bf16
  if (ws_size < WT_BYTES + XB_BYTES + per_batch) return;
  int nb_max = (int)((ws_size - WT_BYTES - XB_BYTES) / per_batch);
  int nb, lgnb;
  if      (nb_max >= 8) { nb = 8; lgnb = 3; }
  else if (nb_max >= 4) { nb = 4; lgnb = 2; }
  else if (nb_max >= 2) { nb = 2; lgnb = 1; }
  else                  { nb = 1; lgnb = 0; }

  hipMemsetAsync(d_out, 0, (size_t)out_size * sizeof(float), stream);
  prep_wt<<<(288 * 64 + 255) / 256, 256, 0, stream>>>(W, WT);
  prep_xb<<<(Bq * Nq * CIN / 4 + 255) / 256, 256, 0, stream>>>(x, xb);

  int nx = (Nq + 63) / 64;                                // 782
  for (int bbase = 0; bbase < Bq; bbase += nb) {
    fused_gather_gemm_elu<<<nx * nb, 256, 0, stream>>>(xb, WT, bias, sidx, h,
                                                       bbase, nb, lgnb);
    long long threads = (long long)NNZq * 32 * nb;        // ushort2 per thread
    scatter_pool<<<(int)((threads + 255) / 256), 256, 0, stream>>>(h, value, row, col,
                                                                   out, bbase, nb, lgnb);
  }
}

// Round 7
// 262.575 us; speedup vs baseline: 1.3981x; 1.3981x over previous
//
#include <hip/hip_runtime.h>
#include <hip/hip_bf16.h>
#include <math.h>

// Problem constants (fixed by the harness)
#define Bq    8
#define Nq    50000
#define CIN   32
#define Sq    9
#define COUT  64
#define MSEG  12500
#define NNZq  50000
#define KSTEPS 9          // 288 / 32

#define WT_BYTES  65536                     // ws: W^T bf16 (36,864 B used)
#define XB_BYTES  ((size_t)Bq*Nq*CIN*2)     // 25.6 MB bf16 x copy
#define CSR_BYTES (4*((size_t)MSEG*3 + NNZq) + 4096)  // cnt,start,fill + eidx

typedef __bf16 bf16x8 __attribute__((ext_vector_type(8)));
typedef float  f32x4  __attribute__((ext_vector_type(4)));

static __device__ __forceinline__ unsigned short f2bf(float f) {
  union { float f; unsigned u; } v; v.f = f;
  unsigned r = v.u + 0x7fffu + ((v.u >> 16) & 1u);   // RNE
  return (unsigned short)(r >> 16);
}

// Prep A: W[288][64] f32 -> WT[64][288] bf16
__global__ __launch_bounds__(256) void prep_wt(const float* __restrict__ W,
                                               unsigned short* __restrict__ WT)
{
  int t = blockIdx.x * 256 + threadIdx.x;
  if (t >= 288 * 64) return;
  int c = t & 63;
  int k = t >> 6;
  WT[c * 288 + k] = f2bf(W[k * 64 + c]);
}

// Prep B: x f32 -> xb bf16
__global__ __launch_bounds__(256) void prep_xb(const float* __restrict__ x,
                                               unsigned short* __restrict__ xb)
{
  int i = blockIdx.x * 256 + threadIdx.x;     // 4 elems/thread; 12500 blocks exact
  float4 v = ((const float4*)x)[i];
  ushort4 p;
  p.x = f2bf(v.x); p.y = f2bf(v.y); p.z = f2bf(v.z); p.w = f2bf(v.w);
  ((ushort4*)xb)[i] = p;
}

// ---- CSR build (row/col static; rebuilt every call, ~10us total) ----
__global__ __launch_bounds__(256) void csr_hist(const int* __restrict__ row,
                                                int* __restrict__ cnt)
{
  int e = blockIdx.x * 256 + threadIdx.x;
  if (e < NNZq) atomicAdd(&cnt[row[e]], 1);
}

__global__ __launch_bounds__(1024) void csr_scan(const int* __restrict__ cnt,
                                                 int* __restrict__ start)
{
  __shared__ int s[1024];
  const int t = threadIdx.x;
  const int PER = (MSEG + 1023) / 1024;       // 13
  int loc[PER];
  int sum = 0;
  #pragma unroll
  for (int i = 0; i < PER; ++i) {
    int r = t * PER + i;
    int v = (r < MSEG) ? cnt[r] : 0;
    loc[i] = sum; sum += v;
  }
  s[t] = sum; __syncthreads();
  for (int off = 1; off < 1024; off <<= 1) {
    int v = (t >= off) ? s[t - off] : 0;
    __syncthreads();
    s[t] += v;
    __syncthreads();
  }
  int pre = (t == 0) ? 0 : s[t - 1];
  #pragma unroll
  for (int i = 0; i < PER; ++i) {
    int r = t * PER + i;
    if (r < MSEG) start[r] = pre + loc[i];
  }
}

__global__ __launch_bounds__(256) void csr_fill(const int* __restrict__ row,
                                                const int* __restrict__ start,
                                                int* __restrict__ fill,
                                                int* __restrict__ eidx)
{
  int e = blockIdx.x * 256 + threadIdx.x;
  if (e >= NNZq) return;
  int r = row[e];
  int p = start[r] + atomicAdd(&fill[r], 1);
  eidx[p] = e;
}

// Kernel 1: fused gather + GEMM(288x64 bf16 MFMA) + bias + ELU -> h (bf16)
__global__ __launch_bounds__(256, 4) void fused_gather_gemm_elu(
    const unsigned short* __restrict__ xb, const unsigned short* __restrict__ WT,
    const float* __restrict__ bias, const int* __restrict__ sidx,
    unsigned short* __restrict__ h, int bbase, int nb, int lgnb)
{
  const int tid  = threadIdx.x;
  const int bid  = blockIdx.x;
  const int bloc = bid & (nb - 1);
  const int n0   = (bid >> lgnb) * 64;
  const int b    = bbase + bloc;

  const int w  = tid >> 6;
  const int l  = tid & 63;
  const int la = l & 15;
  const int kg = l >> 4;

  int nrow   = n0 + w * 16 + la;
  int nclamp = nrow < Nq ? nrow : Nq - 1;

  int idxs[KSTEPS];
  #pragma unroll
  for (int s = 0; s < KSTEPS; ++s) idxs[s] = sidx[nclamp * Sq + s];

  const unsigned short* xbb = xb + (size_t)b * Nq * CIN + kg * 8;
  const __bf16* wb = (const __bf16*)WT + la * 288 + kg * 8;

  f32x4 acc[4];
  #pragma unroll
  for (int i = 0; i < 4; ++i) acc[i] = (f32x4){0.f, 0.f, 0.f, 0.f};

  #pragma unroll
  for (int ks = 0; ks < KSTEPS; ++ks) {
    bf16x8 a = *(const bf16x8*)(xbb + (size_t)idxs[ks] * CIN);
    #pragma unroll
    for (int ct = 0; ct < 4; ++ct) {
      bf16x8 bb = *(const bf16x8*)(wb + ct * 16 * 288 + ks * 32);
      acc[ct] = __builtin_amdgcn_mfma_f32_16x16x32_bf16(a, bb, acc[ct], 0, 0, 0);
    }
  }

  #pragma unroll
  for (int ct = 0; ct < 4; ++ct) {
    int cn = ct * 16 + la;
    float bv = bias[cn];
    #pragma unroll
    for (int r = 0; r < 4; ++r) {
      int n = n0 + w * 16 + kg * 4 + r;     // D: row = 4*(lane>>4)+reg, col = lane&15
      if (n < Nq) {
        float v = acc[ct][r] + bv;
        v = v > 0.f ? v : (__expf(v) - 1.0f);  // ELU(alpha=1)
        h[((size_t)n * nb + bloc) * COUT + cn] = f2bf(v);
      }
    }
  }
}

// Kernel 2: CSR pool — block per segment row, threads=(bloc,c). No atomics:
// each out element written exactly once (also covers empty rows with 0).
__global__ __launch_bounds__(512) void csr_pool(
    const unsigned short* __restrict__ h, const float* __restrict__ value,
    const int* __restrict__ col, const int* __restrict__ start,
    const int* __restrict__ cnt, const int* __restrict__ eidx,
    float* __restrict__ out, int bbase, int nb)
{
  int r    = blockIdx.x;
  int c    = threadIdx.x & 63;
  int bloc = threadIdx.x >> 6;               // 0..nb-1
  int s0 = start[r];
  int ne = cnt[r];
  float acc = 0.f;
  for (int j = 0; j < ne; ++j) {
    int e = eidx[s0 + j];
    float v = value[e];
    int cc = col[e];
    unsigned short hv = h[((size_t)cc * nb + bloc) * COUT + c];
    acc += v * __bfloat162float(*(const __hip_bfloat16*)&hv);
  }
  out[((size_t)(bbase + bloc) * MSEG + r) * COUT + c] = acc;
}

extern "C" void kernel_launch(void* const* d_in, const int* in_sizes, int n_in,
                              void* d_out, int out_size, void* d_ws, size_t ws_size,
                              hipStream_t stream)
{
  const float* x     = (const float*)d_in[0];
  const float* W     = (const float*)d_in[1];
  const float* bias  = (const float*)d_in[2];
  const float* value = (const float*)d_in[3];
  const int*   sidx  = (const int*)d_in[4];
  const int*   row   = (const int*)d_in[5];
  const int*   col   = (const int*)d_in[6];
  float* out = (float*)d_out;

  char* p = (char*)d_ws;
  unsigned short* WT = (unsigned short*)p;          p += WT_BYTES;
  unsigned short* xb = (unsigned short*)p;          p += XB_BYTES;
  int* cnt   = (int*)p;                             p += 4 * MSEG;
  int* fill  = (int*)p;                             p += 4 * MSEG;
  int* start = (int*)p;                             p += 4 * MSEG;
  int* eidx  = (int*)p;                             p += 4 * NNZq;
  unsigned short* h = (unsigned short*)p;

  size_t fixed = (size_t)(p - (char*)d_ws);
  size_t per_batch = (size_t)Nq * COUT * 2;         // 6.4 MB bf16
  if (ws_size < fixed + per_batch) return;
  int nb_max = (int)((ws_size - fixed) / per_batch);
  int nb, lgnb;
  if      (nb_max >= 8) { nb = 8; lgnb = 3; }
  else if (nb_max >= 4) { nb = 4; lgnb = 2; }
  else if (nb_max >= 2) { nb = 2; lgnb = 1; }
  else                  { nb = 1; lgnb = 0; }

  // zero cnt+fill (adjacent -> one memset); no d_out memset needed (pool writes all)
  hipMemsetAsync(cnt, 0, 8 * MSEG, stream);
  prep_wt<<<(288 * 64 + 255) / 256, 256, 0, stream>>>(W, WT);
  prep_xb<<<Bq * Nq * CIN / 4 / 256, 256, 0, stream>>>(x, xb);
  csr_hist<<<(NNZq + 255) / 256, 256, 0, stream>>>(row, cnt);
  csr_scan<<<1, 1024, 0, stream>>>(cnt, start);
  csr_fill<<<(NNZq + 255) / 256, 256, 0, stream>>>(row, start, fill, eidx);

  int nx = (Nq + 63) / 64;                          // 782
  for (int bbase = 0; bbase < Bq; bbase += nb) {
    fused_gather_gemm_elu<<<nx * nb, 256, 0, stream>>>(xb, WT, bias, sidx, h,
                                                       bbase, nb, lgnb);
    csr_pool<<<MSEG, nb * 64, 0, stream>>>(h, value, col, start, cnt, eidx,
                                           out, bbase, nb);
  }
}

// Round 9
// 239.678 us; speedup vs baseline: 1.5317x; 1.0955x over previous
//
#include <hip/hip_runtime.h>
#include <hip/hip_bf16.h>
#include <math.h>

// Problem constants (fixed by the harness)
#define Bq    8
#define Nq    50000
#define CIN   32
#define Sq    9
#define COUT  64
#define MSEG  12500
#define NNZq  50000
#define KSTEPS 9          // 288 / 32

#define WT_BYTES  65536                     // ws: W^T bf16 (36,864 B used)
#define XB_BYTES  ((size_t)Bq*Nq*CIN*2)     // 25.6 MB bf16 x copy

typedef __bf16 bf16x8 __attribute__((ext_vector_type(8)));
typedef float  f32x4  __attribute__((ext_vector_type(4)));

static __device__ __forceinline__ unsigned short f2bf(float f) {
  union { float f; unsigned u; } v; v.f = f;
  unsigned r = v.u + 0x7fffu + ((v.u >> 16) & 1u);   // RNE
  return (unsigned short)(r >> 16);
}

// Prep A: W[288][64] f32 -> WT bf16, channel-PERMUTED so that MFMA tile ct,
// fragment lane la computes output channel 4*la+ct:
//   WT row j = (c&3)*16 + (c>>2)  holds original channel c.
__global__ __launch_bounds__(256) void prep_wt(const float* __restrict__ W,
                                               unsigned short* __restrict__ WT)
{
  int t = blockIdx.x * 256 + threadIdx.x;
  if (t >= 288 * 64) return;
  int c = t & 63;
  int k = t >> 6;
  int j = (c & 3) * 16 + (c >> 2);
  WT[j * 288 + k] = f2bf(W[k * 64 + c]);
}

// Prep B: x f32 -> xb bf16
__global__ __launch_bounds__(256) void prep_xb(const float* __restrict__ x,
                                               unsigned short* __restrict__ xb)
{
  int i = blockIdx.x * 256 + threadIdx.x;     // 4 elems/thread; exact grid
  float4 v = ((const float4*)x)[i];
  ushort4 p;
  p.x = f2bf(v.x); p.y = f2bf(v.y); p.z = f2bf(v.z); p.w = f2bf(v.w);
  ((ushort4*)xb)[i] = p;
}

// ---- CSR build (row/col static; rebuilt every call, ~10us total) ----
__global__ __launch_bounds__(256) void csr_hist(const int* __restrict__ row,
                                                int* __restrict__ cnt)
{
  int e = blockIdx.x * 256 + threadIdx.x;
  if (e < NNZq) atomicAdd(&cnt[row[e]], 1);
}

__global__ __launch_bounds__(1024) void csr_scan(const int* __restrict__ cnt,
                                                 int* __restrict__ start)
{
  __shared__ int s[1024];
  const int t = threadIdx.x;
  const int PER = (MSEG + 1023) / 1024;       // 13
  int loc[PER];
  int sum = 0;
  #pragma unroll
  for (int i = 0; i < PER; ++i) {
    int r = t * PER + i;
    int v = (r < MSEG) ? cnt[r] : 0;
    loc[i] = sum; sum += v;
  }
  s[t] = sum; __syncthreads();
  for (int off = 1; off < 1024; off <<= 1) {
    int v = (t >= off) ? s[t - off] : 0;
    __syncthreads();
    s[t] += v;
    __syncthreads();
  }
  int pre = (t == 0) ? 0 : s[t - 1];
  #pragma unroll
  for (int i = 0; i < PER; ++i) {
    int r = t * PER + i;
    if (r < MSEG) start[r] = pre + loc[i];
  }
}

__global__ __launch_bounds__(256) void csr_fill(const int* __restrict__ row,
                                                const int* __restrict__ start,
                                                int* __restrict__ fill,
                                                int* __restrict__ eidx)
{
  int e = blockIdx.x * 256 + threadIdx.x;
  if (e >= NNZq) return;
  int r = row[e];
  int p = start[r] + atomicAdd(&fill[r], 1);
  eidx[p] = e;
}

// Kernel 1: fused gather + GEMM(288x64 bf16 MFMA) + bias + ELU -> h (bf16).
// All 9 A-fragments preloaded (9 gathers in flight); h written as ushort4
// (channel permutation folded into WT) -> 128B contiguous per row.
__global__ __launch_bounds__(256, 4) void fused_gather_gemm_elu(
    const unsigned short* __restrict__ xb, const unsigned short* __restrict__ WT,
    const float* __restrict__ bias, const int* __restrict__ sidx,
    unsigned short* __restrict__ h, int bbase, int nb, int lgnb)
{
  const int tid  = threadIdx.x;
  const int bid  = blockIdx.x;
  const int bloc = bid & (nb - 1);
  const int n0   = (bid >> lgnb) * 64;
  const int b    = bbase + bloc;

  const int w  = tid >> 6;
  const int l  = tid & 63;
  const int la = l & 15;
  const int kg = l >> 4;

  int nrow   = n0 + w * 16 + la;
  int nclamp = nrow < Nq ? nrow : Nq - 1;

  int idxs[KSTEPS];
  #pragma unroll
  for (int s = 0; s < KSTEPS; ++s) idxs[s] = sidx[nclamp * Sq + s];

  const unsigned short* xbb = xb + (size_t)b * Nq * CIN + kg * 8;
  const __bf16* wb = (const __bf16*)WT + la * 288 + kg * 8;

  // ---- all 9 gathers issued before any use: MLP depth 9 ----
  bf16x8 afr[KSTEPS];
  #pragma unroll
  for (int ks = 0; ks < KSTEPS; ++ks)
    afr[ks] = *(const bf16x8*)(xbb + (size_t)idxs[ks] * CIN);

  f32x4 acc[4];
  #pragma unroll
  for (int i = 0; i < 4; ++i) acc[i] = (f32x4){0.f, 0.f, 0.f, 0.f};

  #pragma unroll
  for (int ks = 0; ks < KSTEPS; ++ks) {
    #pragma unroll
    for (int ct = 0; ct < 4; ++ct) {
      bf16x8 bb = *(const bf16x8*)(wb + ct * 16 * 288 + ks * 32);
      acc[ct] = __builtin_amdgcn_mfma_f32_16x16x32_bf16(afr[ks], bb, acc[ct], 0, 0, 0);
    }
  }

  // epilogue: acc[ct][r] is channel 4*la+ct of row n0+w*16+kg*4+r.
  float4 b4 = ((const float4*)bias)[la];      // bias[4la..4la+3] == ct 0..3
  #pragma unroll
  for (int r = 0; r < 4; ++r) {
    int n = n0 + w * 16 + kg * 4 + r;
    if (n < Nq) {
      float v0 = acc[0][r] + b4.x;
      float v1 = acc[1][r] + b4.y;
      float v2 = acc[2][r] + b4.z;
      float v3 = acc[3][r] + b4.w;
      v0 = v0 > 0.f ? v0 : (__expf(v0) - 1.0f);
      v1 = v1 > 0.f ? v1 : (__expf(v1) - 1.0f);
      v2 = v2 > 0.f ? v2 : (__expf(v2) - 1.0f);
      v3 = v3 > 0.f ? v3 : (__expf(v3) - 1.0f);
      ushort4 pk;
      pk.x = f2bf(v0); pk.y = f2bf(v1); pk.z = f2bf(v2); pk.w = f2bf(v3);
      *(ushort4*)&h[((size_t)n * nb + bloc) * COUT + 4 * la] = pk;   // 8B store
    }
  }
}

// Kernel 2: CSR pool — block per segment row, threads=(bloc,c). No atomics;
// 4-deep edge unroll for memory-level parallelism.
__global__ __launch_bounds__(512) void csr_pool(
    const unsigned short* __restrict__ h, const float* __restrict__ value,
    const int* __restrict__ col, const int* __restrict__ start,
    const int* __restrict__ cnt, const int* __restrict__ eidx,
    float* __restrict__ out, int bbase, int nb)
{
  int r    = blockIdx.x;
  int c    = threadIdx.x & 63;
  int bloc = threadIdx.x >> 6;               // 0..nb-1
  int s0 = start[r];
  int ne = cnt[r];
  float acc = 0.f;
  int j = 0;
  for (; j + 4 <= ne; j += 4) {
    int e0 = eidx[s0+j], e1 = eidx[s0+j+1], e2 = eidx[s0+j+2], e3 = eidx[s0+j+3];
    int   c0 = col[e0],   c1 = col[e1],   c2 = col[e2],   c3 = col[e3];
    float v0 = value[e0], v1 = value[e1], v2 = value[e2], v3 = value[e3];
    unsigned short h0 = h[((size_t)c0 * nb + bloc) * COUT + c];
    unsigned short h1 = h[((size_t)c1 * nb + bloc) * COUT + c];
    unsigned short h2 = h[((size_t)c2 * nb + bloc) * COUT + c];
    unsigned short h3 = h[((size_t)c3 * nb + bloc) * COUT + c];
    acc += v0 * __bfloat162float(*(const __hip_bfloat16*)&h0)
         + v1 * __bfloat162float(*(const __hip_bfloat16*)&h1)
         + v2 * __bfloat162float(*(const __hip_bfloat16*)&h2)
         + v3 * __bfloat162float(*(const __hip_bfloat16*)&h3);
  }
  for (; j < ne; ++j) {
    int e = eidx[s0 + j];
    float v = value[e];
    int cc = col[e];
    unsigned short hv = h[((size_t)cc * nb + bloc) * COUT + c];
    acc += v * __bfloat162float(*(const __hip_bfloat16*)&hv);
  }
  out[((size_t)(bbase + bloc) * MSEG + r) * COUT + c] = acc;
}

extern "C" void kernel_launch(void* const* d_in, const int* in_sizes, int n_in,
                              void* d_out, int out_size, void* d_ws, size_t ws_size,
                              hipStream_t stream)
{
  const float* x     = (const float*)d_in[0];
  const float* W     = (const float*)d_in[1];
  const float* bias  = (const float*)d_in[2];
  const float* value = (const float*)d_in[3];
  const int*   sidx  = (const int*)d_in[4];
  const int*   row   = (const int*)d_in[5];
  const int*   col   = (const int*)d_in[6];
  float* out = (float*)d_out;

  char* p = (char*)d_ws;
  unsigned short* WT = (unsigned short*)p;          p += WT_BYTES;
  unsigned short* xb = (unsigned short*)p;          p += XB_BYTES;
  int* cnt   = (int*)p;                             p += 4 * MSEG;
  int* fill  = (int*)p;                             p += 4 * MSEG;
  int* start = (int*)p;                             p += 4 * MSEG;
  int* eidx  = (int*)p;                             p += 4 * NNZq;
  unsigned short* h = (unsigned short*)p;

  size_t fixed = (size_t)(p - (char*)d_ws);
  size_t per_batch = (size_t)Nq * COUT * 2;         // 6.4 MB bf16
  if (ws_size < fixed + per_batch) return;
  int nb_max = (int)((ws_size - fixed) / per_batch);
  int nb, lgnb;
  if      (nb_max >= 8) { nb = 8; lgnb = 3; }
  else if (nb_max >= 4) { nb = 4; lgnb = 2; }
  else if (nb_max >= 2) { nb = 2; lgnb = 1; }
  else                  { nb = 1; lgnb = 0; }

  hipMemsetAsync(cnt, 0, 8 * MSEG, stream);         // cnt+fill adjacent
  prep_wt<<<(288 * 64 + 255) / 256, 256, 0, stream>>>(W, WT);
  prep_xb<<<Bq * Nq * CIN / 4 / 256, 256, 0, stream>>>(x, xb);
  csr_hist<<<(NNZq + 255) / 256, 256, 0, stream>>>(row, cnt);
  csr_scan<<<1, 1024, 0, stream>>>(cnt, start);
  csr_fill<<<(NNZq + 255) / 256, 256, 0, stream>>>(row, start, fill, eidx);

  int nx = (Nq + 63) / 64;                          // 782
  for (int bbase = 0; bbase < Bq; bbase += nb) {
    fused_gather_gemm_elu<<<nx * nb, 256, 0, stream>>>(xb, WT, bias, sidx, h,
                                                       bbase, nb, lgnb);
    csr_pool<<<MSEG, nb * 64, 0, stream>>>(h, value, col, start, cnt, eidx,
                                           out, bbase, nb);
  }
}

// Round 10
// 230.293 us; speedup vs baseline: 1.5941x; 1.0408x over previous
//
#include <hip/hip_runtime.h>
#include <hip/hip_bf16.h>
#include <math.h>

// Problem constants (fixed by the harness)
#define Bq    8
#define Nq    50000
#define CIN   32
#define Sq    9
#define COUT  64
#define MSEG  12500
#define NNZq  50000
#define KSTEPS 9          // 288 / 32

#define WT_BYTES  65536                     // ws: W^T bf16 (36,864 B used)
#define XB_BYTES  ((size_t)Bq*Nq*CIN*2)     // 25.6 MB bf16 x copy

typedef __bf16 bf16x8 __attribute__((ext_vector_type(8)));
typedef float  f32x4  __attribute__((ext_vector_type(4)));

static __device__ __forceinline__ unsigned short f2bf(float f) {
  union { float f; unsigned u; } v; v.f = f;
  unsigned r = v.u + 0x7fffu + ((v.u >> 16) & 1u);   // RNE
  return (unsigned short)(r >> 16);
}

// Prep A: W[288][64] f32 -> WT bf16, channel-PERMUTED so that MFMA tile ct,
// fragment lane la computes output channel 4*la+ct (WT row j=(c&3)*16+(c>>2)).
__global__ __launch_bounds__(256) void prep_wt(const float* __restrict__ W,
                                               unsigned short* __restrict__ WT)
{
  int t = blockIdx.x * 256 + threadIdx.x;
  if (t >= 288 * 64) return;
  int c = t & 63;
  int k = t >> 6;
  int j = (c & 3) * 16 + (c >> 2);
  WT[j * 288 + k] = f2bf(W[k * 64 + c]);
}

// Prep B: x f32 -> xb bf16
__global__ __launch_bounds__(256) void prep_xb(const float* __restrict__ x,
                                               unsigned short* __restrict__ xb)
{
  int i = blockIdx.x * 256 + threadIdx.x;     // 4 elems/thread; exact grid
  float4 v = ((const float4*)x)[i];
  ushort4 p;
  p.x = f2bf(v.x); p.y = f2bf(v.y); p.z = f2bf(v.z); p.w = f2bf(v.w);
  ((ushort4*)xb)[i] = p;
}

// ---- CSR build (row/col static; rebuilt every call, ~10us total) ----
__global__ __launch_bounds__(256) void csr_hist(const int* __restrict__ row,
                                                int* __restrict__ cnt)
{
  int e = blockIdx.x * 256 + threadIdx.x;
  if (e < NNZq) atomicAdd(&cnt[row[e]], 1);
}

__global__ __launch_bounds__(1024) void csr_scan(const int* __restrict__ cnt,
                                                 int* __restrict__ start)
{
  __shared__ int s[1024];
  const int t = threadIdx.x;
  const int PER = (MSEG + 1023) / 1024;       // 13
  int loc[PER];
  int sum = 0;
  #pragma unroll
  for (int i = 0; i < PER; ++i) {
    int r = t * PER + i;
    int v = (r < MSEG) ? cnt[r] : 0;
    loc[i] = sum; sum += v;
  }
  s[t] = sum; __syncthreads();
  for (int off = 1; off < 1024; off <<= 1) {
    int v = (t >= off) ? s[t - off] : 0;
    __syncthreads();
    s[t] += v;
    __syncthreads();
  }
  int pre = (t == 0) ? 0 : s[t - 1];
  #pragma unroll
  for (int i = 0; i < PER; ++i) {
    int r = t * PER + i;
    if (r < MSEG) start[r] = pre + loc[i];
  }
}

// Fill packed (col, value) pairs in CSR order: removes one indirection level
// from the pool's dependent-load chain.
__global__ __launch_bounds__(256) void csr_fill(const int* __restrict__ row,
                                                const int* __restrict__ col,
                                                const float* __restrict__ value,
                                                const int* __restrict__ start,
                                                int* __restrict__ fill,
                                                int2* __restrict__ cv)
{
  int e = blockIdx.x * 256 + threadIdx.x;
  if (e >= NNZq) return;
  int r = row[e];
  int p = start[r] + atomicAdd(&fill[r], 1);
  int2 pk;
  pk.x = col[e];
  pk.y = __float_as_int(value[e]);
  cv[p] = pk;
}

// Kernel 1: fused gather + GEMM(288x64 bf16 MFMA) + bias + ELU -> h (bf16).
// sched_barrier(0) pins all 9 gathers in flight (MLP=9). h layout [bloc][n][c]:
// each wave stores 16 consecutive rows = 2KB contiguous (full-line writes).
__global__ __launch_bounds__(256, 4) void fused_gather_gemm_elu(
    const unsigned short* __restrict__ xb, const unsigned short* __restrict__ WT,
    const float* __restrict__ bias, const int* __restrict__ sidx,
    unsigned short* __restrict__ h, int bbase, int nb, int lgnb)
{
  const int tid  = threadIdx.x;
  const int bid  = blockIdx.x;
  const int bloc = bid & (nb - 1);
  const int n0   = (bid >> lgnb) * 64;
  const int b    = bbase + bloc;

  const int w  = tid >> 6;
  const int l  = tid & 63;
  const int la = l & 15;
  const int kg = l >> 4;

  int nrow   = n0 + w * 16 + la;
  int nclamp = nrow < Nq ? nrow : Nq - 1;

  int idxs[KSTEPS];
  #pragma unroll
  for (int s = 0; s < KSTEPS; ++s) idxs[s] = sidx[nclamp * Sq + s];

  const unsigned short* xbb = xb + (size_t)b * Nq * CIN + kg * 8;
  const __bf16* wb = (const __bf16*)WT + la * 288 + kg * 8;

  // ---- all 9 gathers issued before any MFMA: scheduler fence enforces it ----
  bf16x8 afr[KSTEPS];
  #pragma unroll
  for (int ks = 0; ks < KSTEPS; ++ks)
    afr[ks] = *(const bf16x8*)(xbb + (size_t)idxs[ks] * CIN);
  __builtin_amdgcn_sched_barrier(0);   // nothing crosses: keeps 9 loads in flight

  f32x4 acc[4];
  #pragma unroll
  for (int i = 0; i < 4; ++i) acc[i] = (f32x4){0.f, 0.f, 0.f, 0.f};

  #pragma unroll
  for (int ks = 0; ks < KSTEPS; ++ks) {
    #pragma unroll
    for (int ct = 0; ct < 4; ++ct) {
      bf16x8 bb = *(const bf16x8*)(wb + ct * 16 * 288 + ks * 32);
      acc[ct] = __builtin_amdgcn_mfma_f32_16x16x32_bf16(afr[ks], bb, acc[ct], 0, 0, 0);
    }
  }

  // epilogue: acc[ct][r] is channel 4*la+ct of row n0+w*16+kg*4+r.
  float4 b4 = ((const float4*)bias)[la];      // bias[4la..4la+3] == ct 0..3
  #pragma unroll
  for (int r = 0; r < 4; ++r) {
    int n = n0 + w * 16 + kg * 4 + r;
    if (n < Nq) {
      float v0 = acc[0][r] + b4.x;
      float v1 = acc[1][r] + b4.y;
      float v2 = acc[2][r] + b4.z;
      float v3 = acc[3][r] + b4.w;
      v0 = v0 > 0.f ? v0 : (__expf(v0) - 1.0f);
      v1 = v1 > 0.f ? v1 : (__expf(v1) - 1.0f);
      v2 = v2 > 0.f ? v2 : (__expf(v2) - 1.0f);
      v3 = v3 > 0.f ? v3 : (__expf(v3) - 1.0f);
      ushort4 pk;
      pk.x = f2bf(v0); pk.y = f2bf(v1); pk.z = f2bf(v2); pk.w = f2bf(v3);
      *(ushort4*)&h[((size_t)bloc * Nq + n) * COUT + 4 * la] = pk;   // 8B store
    }
  }
}

// Kernel 2: CSR pool — block per segment row, threads=(bloc,c). No atomics;
// packed (col,value) pairs; 4-deep edge unroll for MLP.
__global__ __launch_bounds__(512) void csr_pool(
    const unsigned short* __restrict__ h, const int2* __restrict__ cv,
    const int* __restrict__ start, const int* __restrict__ cnt,
    float* __restrict__ out, int bbase, int nb)
{
  int r    = blockIdx.x;
  int c    = threadIdx.x & 63;
  int bloc = threadIdx.x >> 6;               // 0..nb-1
  const unsigned short* hb = h + (size_t)bloc * Nq * COUT + c;
  int s0 = start[r];
  int ne = cnt[r];
  float acc = 0.f;
  int j = 0;
  for (; j + 4 <= ne; j += 4) {
    int2 p0 = cv[s0+j], p1 = cv[s0+j+1], p2 = cv[s0+j+2], p3 = cv[s0+j+3];
    unsigned short h0 = hb[(size_t)p0.x * COUT];
    unsigned short h1 = hb[(size_t)p1.x * COUT];
    unsigned short h2 = hb[(size_t)p2.x * COUT];
    unsigned short h3 = hb[(size_t)p3.x * COUT];
    acc += __int_as_float(p0.y) * __bfloat162float(*(const __hip_bfloat16*)&h0)
         + __int_as_float(p1.y) * __bfloat162float(*(const __hip_bfloat16*)&h1)
         + __int_as_float(p2.y) * __bfloat162float(*(const __hip_bfloat16*)&h2)
         + __int_as_float(p3.y) * __bfloat162float(*(const __hip_bfloat16*)&h3);
  }
  for (; j < ne; ++j) {
    int2 pk = cv[s0 + j];
    unsigned short hv = hb[(size_t)pk.x * COUT];
    acc += __int_as_float(pk.y) * __bfloat162float(*(const __hip_bfloat16*)&hv);
  }
  out[((size_t)(bbase + bloc) * MSEG + r) * COUT + c] = acc;
}

extern "C" void kernel_launch(void* const* d_in, const int* in_sizes, int n_in,
                              void* d_out, int out_size, void* d_ws, size_t ws_size,
                              hipStream_t stream)
{
  const float* x     = (const float*)d_in[0];
  const float* W     = (const float*)d_in[1];
  const float* bias  = (const float*)d_in[2];
  const float* value = (const float*)d_in[3];
  const int*   sidx  = (const int*)d_in[4];
  const int*   row   = (const int*)d_in[5];
  const int*   col   = (const int*)d_in[6];
  float* out = (float*)d_out;

  char* p = (char*)d_ws;
  unsigned short* WT = (unsigned short*)p;          p += WT_BYTES;
  unsigned short* xb = (unsigned short*)p;          p += XB_BYTES;
  int* cnt   = (int*)p;                             p += 4 * MSEG;
  int* fill  = (int*)p;                             p += 4 * MSEG;
  int* start = (int*)p;                             p += 4 * MSEG;
  int2* cv   = (int2*)p;                            p += 8 * NNZq;
  unsigned short* h = (unsigned short*)p;

  size_t fixed = (size_t)(p - (char*)d_ws);
  size_t per_batch = (size_t)Nq * COUT * 2;         // 6.4 MB bf16
  if (ws_size < fixed + per_batch) return;
  int nb_max = (int)((ws_size - fixed) / per_batch);
  int nb, lgnb;
  if      (nb_max >= 8) { nb = 8; lgnb = 3; }
  else if (nb_max >= 4) { nb = 4; lgnb = 2; }
  else if (nb_max >= 2) { nb = 2; lgnb = 1; }
  else                  { nb = 1; lgnb = 0; }

  hipMemsetAsync(cnt, 0, 8 * MSEG, stream);         // cnt+fill adjacent
  prep_wt<<<(288 * 64 + 255) / 256, 256, 0, stream>>>(W, WT);
  prep_xb<<<Bq * Nq * CIN / 4 / 256, 256, 0, stream>>>(x, xb);
  csr_hist<<<(NNZq + 255) / 256, 256, 0, stream>>>(row, cnt);
  csr_scan<<<1, 1024, 0, stream>>>(cnt, start);
  csr_fill<<<(NNZq + 255) / 256, 256, 0, stream>>>(row, col, value, start, fill, cv);

  int nx = (Nq + 63) / 64;                          // 782
  for (int bbase = 0; bbase < Bq; bbase += nb) {
    fused_gather_gemm_elu<<<nx * nb, 256, 0, stream>>>(xb, WT, bias, sidx, h,
                                                       bbase, nb, lgnb);
    csr_pool<<<MSEG, nb * 64, 0, stream>>>(h, cv, start, cnt, out, bbase, nb);
  }
}

// Round 11
// 196.484 us; speedup vs baseline: 1.8684x; 1.1721x over previous
//
#include <hip/hip_runtime.h>
#include <hip/hip_bf16.h>
#include <math.h>

// Problem constants (fixed by the harness)
#define Bq    8
#define Nq    50000
#define CIN   32
#define Sq    9
#define COUT  64
#define MSEG  12500
#define NNZq  50000
#define KSTEPS 9          // 288 / 32

#define WT_BYTES  65536                     // ws: W fragment-order bf16 (36,864 B used)
#define XB_BYTES  ((size_t)Bq*Nq*CIN*2)     // 25.6 MB bf16 x copy
#define S12_BYTES ((size_t)Nq*12*4)         // 2.4 MB padded sidx

typedef __bf16 bf16x8 __attribute__((ext_vector_type(8)));
typedef float  f32x4  __attribute__((ext_vector_type(4)));

static __device__ __forceinline__ unsigned short f2bf(float f) {
  union { float f; unsigned u; } v; v.f = f;
  unsigned r = v.u + 0x7fffu + ((v.u >> 16) & 1u);   // RNE
  return (unsigned short)(r >> 16);
}

// Prep A: W[288][64] f32 -> WTf bf16 in PER-LANE FRAGMENT ORDER:
// WTf[((ks*4+ct)*64 + lane)*8 + j] = W[k=ks*32+(lane>>4)*8+j][c=4*(lane&15)+ct].
// Kernel then ds_reads B conflict-free; MFMA tile ct lane la -> channel 4*la+ct.
__global__ __launch_bounds__(256) void prep_wt(const float* __restrict__ W,
                                               unsigned short* __restrict__ WTf)
{
  int t = blockIdx.x * 256 + threadIdx.x;     // 36*64*8 = 18432 exact
  int j    = t & 7;
  int lane = (t >> 3) & 63;
  int m    = t >> 9;                          // ks*4+ct, 0..35
  int ks = m >> 2, ct = m & 3;
  int kg = lane >> 4, la = lane & 15;
  int k = ks * 32 + kg * 8 + j;
  int c = 4 * la + ct;
  WTf[t] = f2bf(W[k * 64 + c]);
}

// Prep B: x f32 -> xb bf16
__global__ __launch_bounds__(256) void prep_xb(const float* __restrict__ x,
                                               unsigned short* __restrict__ xb)
{
  int i = blockIdx.x * 256 + threadIdx.x;     // 4 elems/thread; exact grid
  float4 v = ((const float4*)x)[i];
  ushort4 p;
  p.x = f2bf(v.x); p.y = f2bf(v.y); p.z = f2bf(v.z); p.w = f2bf(v.w);
  ((ushort4*)xb)[i] = p;
}

// Prep C: sidx[n*9+s] -> sidx12[n*12+s] (pad 3) so rows are 3 aligned int4s.
__global__ __launch_bounds__(256) void prep_sidx12(const int* __restrict__ sidx,
                                                   int* __restrict__ sidx12)
{
  int t = blockIdx.x * 256 + threadIdx.x;
  if (t >= Nq * 12) return;
  int n = t / 12;
  int s = t - n * 12;
  sidx12[t] = (s < 9) ? sidx[n * 9 + s] : 0;
}

// ---- CSR build (row/col static; rebuilt every call, ~10us total) ----
__global__ __launch_bounds__(256) void csr_hist(const int* __restrict__ row,
                                                int* __restrict__ cnt)
{
  int e = blockIdx.x * 256 + threadIdx.x;
  if (e < NNZq) atomicAdd(&cnt[row[e]], 1);
}

__global__ __launch_bounds__(1024) void csr_scan(const int* __restrict__ cnt,
                                                 int* __restrict__ start)
{
  __shared__ int s[1024];
  const int t = threadIdx.x;
  const int PER = (MSEG + 1023) / 1024;       // 13
  int loc[PER];
  int sum = 0;
  #pragma unroll
  for (int i = 0; i < PER; ++i) {
    int r = t * PER + i;
    int v = (r < MSEG) ? cnt[r] : 0;
    loc[i] = sum; sum += v;
  }
  s[t] = sum; __syncthreads();
  for (int off = 1; off < 1024; off <<= 1) {
    int v = (t >= off) ? s[t - off] : 0;
    __syncthreads();
    s[t] += v;
    __syncthreads();
  }
  int pre = (t == 0) ? 0 : s[t - 1];
  #pragma unroll
  for (int i = 0; i < PER; ++i) {
    int r = t * PER + i;
    if (r < MSEG) start[r] = pre + loc[i];
  }
}

__global__ __launch_bounds__(256) void csr_fill(const int* __restrict__ row,
                                                const int* __restrict__ col,
                                                const float* __restrict__ value,
                                                const int* __restrict__ start,
                                                int* __restrict__ fill,
                                                int2* __restrict__ cv)
{
  int e = blockIdx.x * 256 + threadIdx.x;
  if (e >= NNZq) return;
  int r = row[e];
  int p = start[r] + atomicAdd(&fill[r], 1);
  int2 pk;
  pk.x = col[e];
  pk.y = __float_as_int(value[e]);
  cv[p] = pk;
}

// Kernel 1: fused gather + GEMM(288x64 bf16 MFMA) + bias + ELU -> h (bf16).
// B staged to LDS in fragment order (ds_read_b128, conflict-free) -> VMEM pipe
// carries only 3 sidx + 9 gathers + 4 stores per wave. Gathers issued AFTER the
// barrier so they stay in flight across the ds_read+MFMA phase.
__global__ __launch_bounds__(256, 4) void fused_gather_gemm_elu(
    const unsigned short* __restrict__ xb, const unsigned short* __restrict__ WTf,
    const float* __restrict__ bias, const int* __restrict__ sidx12,
    unsigned short* __restrict__ h, int bbase, int nb, int lgnb)
{
  __shared__ unsigned short Bl[36 * 64 * 8];   // 36 KB

  const int tid  = threadIdx.x;
  const int bid  = blockIdx.x;
  const int bloc = bid & (nb - 1);
  const int n0   = (bid >> lgnb) * 64;
  const int b    = bbase + bloc;

  // stage B fragments (once per block; 9 int4 per thread, lane-consecutive)
  {
    const int4* src = (const int4*)WTf;
    int4* dst = (int4*)Bl;
    #pragma unroll
    for (int i = 0; i < 9; ++i) dst[i * 256 + tid] = src[i * 256 + tid];
  }
  __syncthreads();   // implicit vmcnt(0) drain happens BEFORE gathers are issued

  const int w  = tid >> 6;
  const int l  = tid & 63;
  const int la = l & 15;
  const int kg = l >> 4;

  int nrow   = n0 + w * 16 + la;
  int nclamp = nrow < Nq ? nrow : Nq - 1;

  // 3 aligned int4 loads of this row's spiral indices
  const int4* sp = (const int4*)(sidx12 + nclamp * 12);
  int4 si0 = sp[0], si1 = sp[1], si2 = sp[2];
  int idxs[KSTEPS] = {si0.x, si0.y, si0.z, si0.w, si1.x, si1.y, si1.z, si1.w, si2.x};

  const unsigned short* xbb = xb + (size_t)b * Nq * CIN + kg * 8;

  // all 9 gathers issued before any MFMA
  bf16x8 afr[KSTEPS];
  #pragma unroll
  for (int ks = 0; ks < KSTEPS; ++ks)
    afr[ks] = *(const bf16x8*)(xbb + (size_t)idxs[ks] * CIN);
  __builtin_amdgcn_sched_barrier(0);

  f32x4 acc[4];
  #pragma unroll
  for (int i = 0; i < 4; ++i) acc[i] = (f32x4){0.f, 0.f, 0.f, 0.f};

  const unsigned short* bl = Bl + l * 8;      // lane-consecutive fragments
  #pragma unroll
  for (int ks = 0; ks < KSTEPS; ++ks) {
    #pragma unroll
    for (int ct = 0; ct < 4; ++ct) {
      bf16x8 bb = *(const bf16x8*)(bl + (ks * 4 + ct) * 512);
      acc[ct] = __builtin_amdgcn_mfma_f32_16x16x32_bf16(afr[ks], bb, acc[ct], 0, 0, 0);
    }
  }

  // epilogue: acc[ct][r] is channel 4*la+ct of row n0+w*16+kg*4+r.
  float4 b4 = ((const float4*)bias)[la];      // bias[4la..4la+3] == ct 0..3
  #pragma unroll
  for (int r = 0; r < 4; ++r) {
    int n = n0 + w * 16 + kg * 4 + r;
    if (n < Nq) {
      float v0 = acc[0][r] + b4.x;
      float v1 = acc[1][r] + b4.y;
      float v2 = acc[2][r] + b4.z;
      float v3 = acc[3][r] + b4.w;
      v0 = v0 > 0.f ? v0 : (__expf(v0) - 1.0f);
      v1 = v1 > 0.f ? v1 : (__expf(v1) - 1.0f);
      v2 = v2 > 0.f ? v2 : (__expf(v2) - 1.0f);
      v3 = v3 > 0.f ? v3 : (__expf(v3) - 1.0f);
      ushort4 pk;
      pk.x = f2bf(v0); pk.y = f2bf(v1); pk.z = f2bf(v2); pk.w = f2bf(v3);
      *(ushort4*)&h[((size_t)bloc * Nq + n) * COUT + 4 * la] = pk;   // 8B store
    }
  }
}

// Kernel 2: CSR pool — block per segment row, threads=(bloc,c). No atomics;
// packed (col,value) pairs; 4-deep edge unroll for MLP.
__global__ __launch_bounds__(512) void csr_pool(
    const unsigned short* __restrict__ h, const int2* __restrict__ cv,
    const int* __restrict__ start, const int* __restrict__ cnt,
    float* __restrict__ out, int bbase, int nb)
{
  int r    = blockIdx.x;
  int c    = threadIdx.x & 63;
  int bloc = threadIdx.x >> 6;               // 0..nb-1
  const unsigned short* hb = h + (size_t)bloc * Nq * COUT + c;
  int s0 = start[r];
  int ne = cnt[r];
  float acc = 0.f;
  int j = 0;
  for (; j + 4 <= ne; j += 4) {
    int2 p0 = cv[s0+j], p1 = cv[s0+j+1], p2 = cv[s0+j+2], p3 = cv[s0+j+3];
    unsigned short h0 = hb[(size_t)p0.x * COUT];
    unsigned short h1 = hb[(size_t)p1.x * COUT];
    unsigned short h2 = hb[(size_t)p2.x * COUT];
    unsigned short h3 = hb[(size_t)p3.x * COUT];
    acc += __int_as_float(p0.y) * __bfloat162float(*(const __hip_bfloat16*)&h0)
         + __int_as_float(p1.y) * __bfloat162float(*(const __hip_bfloat16*)&h1)
         + __int_as_float(p2.y) * __bfloat162float(*(const __hip_bfloat16*)&h2)
         + __int_as_float(p3.y) * __bfloat162float(*(const __hip_bfloat16*)&h3);
  }
  for (; j < ne; ++j) {
    int2 pk = cv[s0 + j];
    unsigned short hv = hb[(size_t)pk.x * COUT];
    acc += __int_as_float(pk.y) * __bfloat162float(*(const __hip_bfloat16*)&hv);
  }
  out[((size_t)(bbase + bloc) * MSEG + r) * COUT + c] = acc;
}

extern "C" void kernel_launch(void* const* d_in, const int* in_sizes, int n_in,
                              void* d_out, int out_size, void* d_ws, size_t ws_size,
                              hipStream_t stream)
{
  const float* x     = (const float*)d_in[0];
  const float* W     = (const float*)d_in[1];
  const float* bias  = (const float*)d_in[2];
  const float* value = (const float*)d_in[3];
  const int*   sidx  = (const int*)d_in[4];
  const int*   row   = (const int*)d_in[5];
  const int*   col   = (const int*)d_in[6];
  float* out = (float*)d_out;

  char* p = (char*)d_ws;
  unsigned short* WTf = (unsigned short*)p;         p += WT_BYTES;
  unsigned short* xb  = (unsigned short*)p;         p += XB_BYTES;
  int* sidx12 = (int*)p;                            p += S12_BYTES;
  int* cnt   = (int*)p;                             p += 4 * MSEG;
  int* fill  = (int*)p;                             p += 4 * MSEG;
  int* start = (int*)p;                             p += 4 * MSEG;
  int2* cv   = (int2*)p;                            p += 8 * NNZq;
  unsigned short* h = (unsigned short*)p;

  size_t fixed = (size_t)(p - (char*)d_ws);
  size_t per_batch = (size_t)Nq * COUT * 2;         // 6.4 MB bf16
  if (ws_size < fixed + per_batch) return;
  int nb_max = (int)((ws_size - fixed) / per_batch);
  int nb, lgnb;
  if      (nb_max >= 8) { nb = 8; lgnb = 3; }
  else if (nb_max >= 4) { nb = 4; lgnb = 2; }
  else if (nb_max >= 2) { nb = 2; lgnb = 1; }
  else                  { nb = 1; lgnb = 0; }

  hipMemsetAsync(cnt, 0, 8 * MSEG, stream);         // cnt+fill adjacent
  prep_wt<<<72, 256, 0, stream>>>(W, WTf);
  prep_xb<<<Bq * Nq * CIN / 4 / 256, 256, 0, stream>>>(x, xb);
  prep_sidx12<<<(Nq * 12 + 255) / 256, 256, 0, stream>>>(sidx, sidx12);
  csr_hist<<<(NNZq + 255) / 256, 256, 0, stream>>>(row, cnt);
  csr_scan<<<1, 1024, 0, stream>>>(cnt, start);
  csr_fill<<<(NNZq + 255) / 256, 256, 0, stream>>>(row, col, value, start, fill, cv);

  int nx = (Nq + 63) / 64;                          // 782
  for (int bbase = 0; bbase < Bq; bbase += nb) {
    fused_gather_gemm_elu<<<nx * nb, 256, 0, stream>>>(xb, WTf, bias, sidx12, h,
                                                       bbase, nb, lgnb);
    csr_pool<<<MSEG, nb * 64, 0, stream>>>(h, cv, start, cnt, out, bbase, nb);
  }
}

// Round 12
// 194.123 us; speedup vs baseline: 1.8911x; 1.0122x over previous
//
#include <hip/hip_runtime.h>
#include <hip/hip_bf16.h>
#include <math.h>

// Problem constants (fixed by the harness)
#define Bq    8
#define Nq    50000
#define CIN   32
#define Sq    9
#define COUT  64
#define MSEG  12500
#define NNZq  50000
#define KSTEPS 9          // 288 / 32

#define WT_BYTES  65536                     // ws: W fragment-order bf16 (36,864 B used)
#define XB_BYTES  ((size_t)Bq*Nq*CIN*2)     // 25.6 MB bf16 x copy
#define S12_BYTES ((size_t)Nq*12*4)         // 2.4 MB padded sidx

typedef __bf16 bf16x8 __attribute__((ext_vector_type(8)));
typedef float  f32x4  __attribute__((ext_vector_type(4)));

static __device__ __forceinline__ unsigned short f2bf(float f) {
  union { float f; unsigned u; } v; v.f = f;
  unsigned r = v.u + 0x7fffu + ((v.u >> 16) & 1u);   // RNE
  return (unsigned short)(r >> 16);
}

// Prep A: W[288][64] f32 -> WTf bf16 in PER-LANE FRAGMENT ORDER:
// WTf[((ks*4+ct)*64 + lane)*8 + j] = W[k=ks*32+(lane>>4)*8+j][c=4*(lane&15)+ct].
__global__ __launch_bounds__(256) void prep_wt(const float* __restrict__ W,
                                               unsigned short* __restrict__ WTf)
{
  int t = blockIdx.x * 256 + threadIdx.x;     // 36*64*8 = 18432 exact
  int j    = t & 7;
  int lane = (t >> 3) & 63;
  int m    = t >> 9;                          // ks*4+ct, 0..35
  int ks = m >> 2, ct = m & 3;
  int kg = lane >> 4, la = lane & 15;
  int k = ks * 32 + kg * 8 + j;
  int c = 4 * la + ct;
  WTf[t] = f2bf(W[k * 64 + c]);
}

// Prep B: x f32 -> xb bf16
__global__ __launch_bounds__(256) void prep_xb(const float* __restrict__ x,
                                               unsigned short* __restrict__ xb)
{
  int i = blockIdx.x * 256 + threadIdx.x;     // 4 elems/thread; exact grid
  float4 v = ((const float4*)x)[i];
  ushort4 p;
  p.x = f2bf(v.x); p.y = f2bf(v.y); p.z = f2bf(v.z); p.w = f2bf(v.w);
  ((ushort4*)xb)[i] = p;
}

// Prep C: sidx[n*9+s] -> sidx12[n*12+s] (pad 3) so rows are 3 aligned int4s.
__global__ __launch_bounds__(256) void prep_sidx12(const int* __restrict__ sidx,
                                                   int* __restrict__ sidx12)
{
  int t = blockIdx.x * 256 + threadIdx.x;
  if (t >= Nq * 12) return;
  int n = t / 12;
  int s = t - n * 12;
  sidx12[t] = (s < 9) ? sidx[n * 9 + s] : 0;
}

// ---- CSR build (row/col static; rebuilt every call, ~10us total) ----
__global__ __launch_bounds__(256) void csr_hist(const int* __restrict__ row,
                                                int* __restrict__ cnt)
{
  int e = blockIdx.x * 256 + threadIdx.x;
  if (e < NNZq) atomicAdd(&cnt[row[e]], 1);
}

__global__ __launch_bounds__(1024) void csr_scan(const int* __restrict__ cnt,
                                                 int* __restrict__ start)
{
  __shared__ int s[1024];
  const int t = threadIdx.x;
  const int PER = (MSEG + 1023) / 1024;       // 13
  int loc[PER];
  int sum = 0;
  #pragma unroll
  for (int i = 0; i < PER; ++i) {
    int r = t * PER + i;
    int v = (r < MSEG) ? cnt[r] : 0;
    loc[i] = sum; sum += v;
  }
  s[t] = sum; __syncthreads();
  for (int off = 1; off < 1024; off <<= 1) {
    int v = (t >= off) ? s[t - off] : 0;
    __syncthreads();
    s[t] += v;
    __syncthreads();
  }
  int pre = (t == 0) ? 0 : s[t - 1];
  #pragma unroll
  for (int i = 0; i < PER; ++i) {
    int r = t * PER + i;
    if (r < MSEG) start[r] = pre + loc[i];
  }
}

__global__ __launch_bounds__(256) void csr_fill(const int* __restrict__ row,
                                                const int* __restrict__ col,
                                                const float* __restrict__ value,
                                                const int* __restrict__ start,
                                                int* __restrict__ fill,
                                                int2* __restrict__ cv)
{
  int e = blockIdx.x * 256 + threadIdx.x;
  if (e >= NNZq) return;
  int r = row[e];
  int p = start[r] + atomicAdd(&fill[r], 1);
  int2 pk;
  pk.x = col[e];
  pk.y = __float_as_int(value[e]);
  cv[p] = pk;
}

// Kernel 1: fused gather + GEMM(288x64 bf16 MFMA) + bias + ELU -> h (bf16).
// 512 threads (8 waves), 128 rows/block: same 36.9KB LDS B-stage now serves
// 8 waves -> 4 blocks/CU = 32 waves/CU (100% static occupancy). Per-wave
// structure identical to round-11 version.
__global__ __launch_bounds__(512, 8) void fused_gather_gemm_elu(
    const unsigned short* __restrict__ xb, const unsigned short* __restrict__ WTf,
    const float* __restrict__ bias, const int* __restrict__ sidx12,
    unsigned short* __restrict__ h, int bbase, int nb, int lgnb)
{
  __shared__ unsigned short Bl[36 * 64 * 8];   // 36 KB

  const int tid  = threadIdx.x;
  const int bid  = blockIdx.x;
  const int bloc = bid & (nb - 1);
  const int n0   = (bid >> lgnb) * 128;
  const int b    = bbase + bloc;

  // stage B fragments (once per block; 9 int2 per thread, lane-consecutive)
  {
    const int2* src = (const int2*)WTf;
    int2* dst = (int2*)Bl;
    #pragma unroll
    for (int i = 0; i < 9; ++i) dst[i * 512 + tid] = src[i * 512 + tid];
  }
  __syncthreads();   // implicit vmcnt(0) drain happens BEFORE gathers are issued

  const int w  = tid >> 6;        // 0..7
  const int l  = tid & 63;
  const int la = l & 15;
  const int kg = l >> 4;

  int nrow   = n0 + w * 16 + la;
  int nclamp = nrow < Nq ? nrow : Nq - 1;

  // 3 aligned int4 loads of this row's spiral indices
  const int4* sp = (const int4*)(sidx12 + nclamp * 12);
  int4 si0 = sp[0], si1 = sp[1], si2 = sp[2];
  int idxs[KSTEPS] = {si0.x, si0.y, si0.z, si0.w, si1.x, si1.y, si1.z, si1.w, si2.x};

  const unsigned short* xbb = xb + (size_t)b * Nq * CIN + kg * 8;

  // all 9 gathers issued before any MFMA
  bf16x8 afr[KSTEPS];
  #pragma unroll
  for (int ks = 0; ks < KSTEPS; ++ks)
    afr[ks] = *(const bf16x8*)(xbb + (size_t)idxs[ks] * CIN);
  __builtin_amdgcn_sched_barrier(0);

  f32x4 acc[4];
  #pragma unroll
  for (int i = 0; i < 4; ++i) acc[i] = (f32x4){0.f, 0.f, 0.f, 0.f};

  const unsigned short* bl = Bl + l * 8;      // lane-consecutive fragments
  #pragma unroll
  for (int ks = 0; ks < KSTEPS; ++ks) {
    #pragma unroll
    for (int ct = 0; ct < 4; ++ct) {
      bf16x8 bb = *(const bf16x8*)(bl + (ks * 4 + ct) * 512);
      acc[ct] = __builtin_amdgcn_mfma_f32_16x16x32_bf16(afr[ks], bb, acc[ct], 0, 0, 0);
    }
  }

  // epilogue: acc[ct][r] is channel 4*la+ct of row n0+w*16+kg*4+r.
  float4 b4 = ((const float4*)bias)[la];      // bias[4la..4la+3] == ct 0..3
  #pragma unroll
  for (int r = 0; r < 4; ++r) {
    int n = n0 + w * 16 + kg * 4 + r;
    if (n < Nq) {
      float v0 = acc[0][r] + b4.x;
      float v1 = acc[1][r] + b4.y;
      float v2 = acc[2][r] + b4.z;
      float v3 = acc[3][r] + b4.w;
      v0 = v0 > 0.f ? v0 : (__expf(v0) - 1.0f);
      v1 = v1 > 0.f ? v1 : (__expf(v1) - 1.0f);
      v2 = v2 > 0.f ? v2 : (__expf(v2) - 1.0f);
      v3 = v3 > 0.f ? v3 : (__expf(v3) - 1.0f);
      ushort4 pk;
      pk.x = f2bf(v0); pk.y = f2bf(v1); pk.z = f2bf(v2); pk.w = f2bf(v3);
      *(ushort4*)&h[((size_t)bloc * Nq + n) * COUT + 4 * la] = pk;   // 8B store
    }
  }
}

// Kernel 2: CSR pool — block per segment row, threads=(bloc,c). No atomics;
// packed (col,value) pairs; 4-deep edge unroll for MLP.
__global__ __launch_bounds__(512) void csr_pool(
    const unsigned short* __restrict__ h, const int2* __restrict__ cv,
    const int* __restrict__ start, const int* __restrict__ cnt,
    float* __restrict__ out, int bbase, int nb)
{
  int r    = blockIdx.x;
  int c    = threadIdx.x & 63;
  int bloc = threadIdx.x >> 6;               // 0..nb-1
  const unsigned short* hb = h + (size_t)bloc * Nq * COUT + c;
  int s0 = start[r];
  int ne = cnt[r];
  float acc = 0.f;
  int j = 0;
  for (; j + 4 <= ne; j += 4) {
    int2 p0 = cv[s0+j], p1 = cv[s0+j+1], p2 = cv[s0+j+2], p3 = cv[s0+j+3];
    unsigned short h0 = hb[(size_t)p0.x * COUT];
    unsigned short h1 = hb[(size_t)p1.x * COUT];
    unsigned short h2 = hb[(size_t)p2.x * COUT];
    unsigned short h3 = hb[(size_t)p3.x * COUT];
    acc += __int_as_float(p0.y) * __bfloat162float(*(const __hip_bfloat16*)&h0)
         + __int_as_float(p1.y) * __bfloat162float(*(const __hip_bfloat16*)&h1)
         + __int_as_float(p2.y) * __bfloat162float(*(const __hip_bfloat16*)&h2)
         + __int_as_float(p3.y) * __bfloat162float(*(const __hip_bfloat16*)&h3);
  }
  for (; j < ne; ++j) {
    int2 pk = cv[s0 + j];
    unsigned short hv = hb[(size_t)pk.x * COUT];
    acc += __int_as_float(pk.y) * __bfloat162float(*(const __hip_bfloat16*)&hv);
  }
  out[((size_t)(bbase + bloc) * MSEG + r) * COUT + c] = acc;
}

extern "C" void kernel_launch(void* const* d_in, const int* in_sizes, int n_in,
                              void* d_out, int out_size, void* d_ws, size_t ws_size,
                              hipStream_t stream)
{
  const float* x     = (const float*)d_in[0];
  const float* W     = (const float*)d_in[1];
  const float* bias  = (const float*)d_in[2];
  const float* value = (const float*)d_in[3];
  const int*   sidx  = (const int*)d_in[4];
  const int*   row   = (const int*)d_in[5];
  const int*   col   = (const int*)d_in[6];
  float* out = (float*)d_out;

  char* p = (char*)d_ws;
  unsigned short* WTf = (unsigned short*)p;         p += WT_BYTES;
  unsigned short* xb  = (unsigned short*)p;         p += XB_BYTES;
  int* sidx12 = (int*)p;                            p += S12_BYTES;
  int* cnt   = (int*)p;                             p += 4 * MSEG;
  int* fill  = (int*)p;                             p += 4 * MSEG;
  int* start = (int*)p;                             p += 4 * MSEG;
  int2* cv   = (int2*)p;                            p += 8 * NNZq;
  unsigned short* h = (unsigned short*)p;

  size_t fixed = (size_t)(p - (char*)d_ws);
  size_t per_batch = (size_t)Nq * COUT * 2;         // 6.4 MB bf16
  if (ws_size < fixed + per_batch) return;
  int nb_max = (int)((ws_size - fixed) / per_batch);
  int nb, lgnb;
  if      (nb_max >= 8) { nb = 8; lgnb = 3; }
  else if (nb_max >= 4) { nb = 4; lgnb = 2; }
  else if (nb_max >= 2) { nb = 2; lgnb = 1; }
  else                  { nb = 1; lgnb = 0; }

  hipMemsetAsync(cnt, 0, 8 * MSEG, stream);         // cnt+fill adjacent
  prep_wt<<<72, 256, 0, stream>>>(W, WTf);
  prep_xb<<<Bq * Nq * CIN / 4 / 256, 256, 0, stream>>>(x, xb);
  prep_sidx12<<<(Nq * 12 + 255) / 256, 256, 0, stream>>>(sidx, sidx12);
  csr_hist<<<(NNZq + 255) / 256, 256, 0, stream>>>(row, cnt);
  csr_scan<<<1, 1024, 0, stream>>>(cnt, start);
  csr_fill<<<(NNZq + 255) / 256, 256, 0, stream>>>(row, col, value, start, fill, cv);

  int nx = (Nq + 127) / 128;                        // 391
  for (int bbase = 0; bbase < Bq; bbase += nb) {
    fused_gather_gemm_elu<<<nx * nb, 512, 0, stream>>>(xb, WTf, bias, sidx12, h,
                                                       bbase, nb, lgnb);
    csr_pool<<<MSEG, nb * 64, 0, stream>>>(h, cv, start, cnt, out, bbase, nb);
  }
}